// Round 6
// baseline (336.324 us; speedup 1.0000x reference)
//
#include <hip/hip_runtime.h>

#define NPAD 256
#define LDSX 1536

typedef float v2f __attribute__((ext_vector_type(2)));

// Sum across 64 lanes via DPP; valid result lands in lane 63. Pure VALU.
__device__ __forceinline__ float wredf(float x) {
  x += __int_as_float(__builtin_amdgcn_update_dpp(0, __float_as_int(x), 0x111, 0xf, 0xf, true)); // row_shr:1
  x += __int_as_float(__builtin_amdgcn_update_dpp(0, __float_as_int(x), 0x112, 0xf, 0xf, true)); // row_shr:2
  x += __int_as_float(__builtin_amdgcn_update_dpp(0, __float_as_int(x), 0x114, 0xf, 0xf, true)); // row_shr:4
  x += __int_as_float(__builtin_amdgcn_update_dpp(0, __float_as_int(x), 0x118, 0xf, 0xf, true)); // row_shr:8
  x += __int_as_float(__builtin_amdgcn_update_dpp(0, __float_as_int(x), 0x142, 0xa, 0xf, true)); // bcast15 rows 1,3
  x += __int_as_float(__builtin_amdgcn_update_dpp(0, __float_as_int(x), 0x143, 0xc, 0xf, true)); // bcast31 rows 2,3
  return x;
}
__device__ __forceinline__ int wredi(int x) {
  x += __builtin_amdgcn_update_dpp(0, x, 0x111, 0xf, 0xf, true);
  x += __builtin_amdgcn_update_dpp(0, x, 0x112, 0xf, 0xf, true);
  x += __builtin_amdgcn_update_dpp(0, x, 0x114, 0xf, 0xf, true);
  x += __builtin_amdgcn_update_dpp(0, x, 0x118, 0xf, 0xf, true);
  x += __builtin_amdgcn_update_dpp(0, x, 0x142, 0xa, 0xf, true);
  x += __builtin_amdgcn_update_dpp(0, x, 0x143, 0xc, 0xf, true);
  return x;
}

// Block = one (n, di, diff). 4 waves; each wave handles 8 groups; 64 lanes
// cover 64 consecutive t per iteration. Packed-f32 (VOP3P) math: kernels are
// paired (2p,2p+1) against a broadcast tap -> v_pk_fma_f32 halves FMA issue.
__global__ void __launch_bounds__(256, 3) hydra_kernel(
    const float* __restrict__ X, const float* __restrict__ W,
    float* __restrict__ out) {
  __shared__ float xs[LDSX];

  const int b = blockIdx.x;
  const int n = b / 14;
  const int r = b - n * 14;          // di*2 + diff
  const int diff = r & 1;
  const int d = 1 << (r >> 1);       // dilation
  const int Lz = 1024 - diff;        // output length (1023 for diff branch)
  const float* xrow = X + n * 1024;
  const int tid = threadIdx.x;

  // Stage padded input row (zeros in [0,256) and [256+Lz,1536))
  for (int i = tid; i < LDSX; i += 256) {
    int t = i - NPAD;
    float v = 0.0f;
    if (t >= 0 && t < Lz) v = diff ? (xrow[t + 1] - xrow[t]) : xrow[t];
    xs[i] = v;
  }
  __syncthreads();

  const int lane = tid & 63;
  const int wv = tid >> 6;
  const float* wb = W + r * 2304;                    // (di,diff) filter bank: 256*9
  float* outb = out + (size_t)n * 7168 + r * 512;    // [cmax(256) | cmin(256)]

  for (int gp = 0; gp < 8; ++gp) {
    const int g = wv * 8 + gp;

    // 72 wave-uniform weights, loaded vectorized then arranged as 4 kernel-pairs:
    // w2[p][j] = { w[2p][j], w[2p+1][j] }  (once per group, amortized over 16 iters)
    float w[72];
    {
      const float4* w4 = (const float4*)(wb + g * 72);
      #pragma unroll
      for (int q = 0; q < 18; ++q) {
        float4 v = w4[q];
        w[q * 4 + 0] = v.x; w[q * 4 + 1] = v.y;
        w[q * 4 + 2] = v.z; w[q * 4 + 3] = v.w;
      }
    }
    v2f w2[36];
    #pragma unroll
    for (int p = 0; p < 4; ++p)
      #pragma unroll
      for (int j = 0; j < 9; ++j)
        w2[p * 9 + j] = (v2f){w[(2 * p) * 9 + j], w[(2 * p + 1) * 9 + j]};

    v2f cmax2[4];
    int cmin[8];
    #pragma unroll
    for (int p = 0; p < 4; ++p) cmax2[p] = (v2f){0.0f, 0.0f};
    #pragma unroll
    for (int k = 0; k < 8; ++k) cmin[k] = 0;

    const int base0 = NPAD - 4 * d + lane;           // index of tap 0 at t=lane

    #pragma unroll 2
    for (int it = 0; it < 16; ++it) {
      const int t = it * 64 + lane;

      // z2[p] = conv of kernel pair (2p, 2p+1); per-kernel tap order identical
      // to scalar version -> bitwise-same z values.
      v2f z2[4];
      {
        float x0 = xs[base0 + it * 64];
        v2f xx0 = (v2f){x0, x0};
        #pragma unroll
        for (int p = 0; p < 4; ++p) z2[p] = w2[p * 9] * xx0;
      }
      #pragma unroll
      for (int j = 1; j < 9; ++j) {
        float xj = xs[base0 + it * 64 + j * d];
        v2f xx = (v2f){xj, xj};
        #pragma unroll
        for (int p = 0; p < 4; ++p)
          z2[p] = __builtin_elementwise_fma(w2[p * 9 + j], xx, z2[p]);
      }

      // packed max/min trees, scalar cross-fold
      v2f mA = __builtin_elementwise_max(__builtin_elementwise_max(z2[0], z2[1]),
                                         __builtin_elementwise_max(z2[2], z2[3]));
      v2f mI = __builtin_elementwise_min(__builtin_elementwise_min(z2[0], z2[1]),
                                         __builtin_elementwise_min(z2[2], z2[3]));
      const float mx = fmaxf(mA.x, mA.y);
      const float mn = fminf(mI.x, mI.y);
      const bool valid = (t < Lz);

      #pragma unroll
      for (int p = 0; p < 4; ++p) {
        cmax2[p].x += (z2[p].x == mx) ? z2[p].x : 0.0f;  // padded tail adds 0
        cmax2[p].y += (z2[p].y == mx) ? z2[p].y : 0.0f;
        cmin[2 * p]     += (valid & (z2[p].x == mn)) ? 1 : 0;
        cmin[2 * p + 1] += (valid & (z2[p].y == mn)) ? 1 : 0;
      }
    }

    float cmax[8];
    #pragma unroll
    for (int p = 0; p < 4; ++p) { cmax[2 * p] = cmax2[p].x; cmax[2 * p + 1] = cmax2[p].y; }
    #pragma unroll
    for (int k = 0; k < 8; ++k) cmax[k] = wredf(cmax[k]);
    int cminr[8];
    #pragma unroll
    for (int k = 0; k < 8; ++k) cminr[k] = wredi(cmin[k]);

    if (lane == 63) {
      float4 a0 = make_float4(cmax[0], cmax[1], cmax[2], cmax[3]);
      float4 a1 = make_float4(cmax[4], cmax[5], cmax[6], cmax[7]);
      float4 b0 = make_float4((float)cminr[0], (float)cminr[1],
                              (float)cminr[2], (float)cminr[3]);
      float4 b1 = make_float4((float)cminr[4], (float)cminr[5],
                              (float)cminr[6], (float)cminr[7]);
      float4* pm = (float4*)(outb + g * 8);
      pm[0] = a0; pm[1] = a1;
      float4* pn = (float4*)(outb + 256 + g * 8);
      pn[0] = b0; pn[1] = b1;
    }
  }
}

extern "C" void kernel_launch(void* const* d_in, const int* in_sizes, int n_in,
                              void* d_out, int out_size, void* d_ws, size_t ws_size,
                              hipStream_t stream) {
  const float* X = (const float*)d_in[0];   // (256,1,1024) f32
  const float* W = (const float*)d_in[1];   // (7,2,256,1,9) f32, normalized
  float* out = (float*)d_out;               // (256,7168) f32
  hydra_kernel<<<dim3(256 * 14), dim3(256), 0, stream>>>(X, W, out);
}